// Round 4
// baseline (90.286 us; speedup 1.0000x reference)
//
#include <hip/hip_runtime.h>
#include <math.h>

#define N_WAY 64
#define N_SUP 16
#define DIM   1024
#define N_QUERIES 4096
#define ROWS_PER_WAY 80
#define QT 16
#define NBLK 256    // one block per 16-query tile; also 4 proto blocks per way

typedef __attribute__((ext_vector_type(8))) short short8;
typedef __attribute__((ext_vector_type(4))) float f32x4;

// Truncation split: v ~= hi + lo (both bf16), error ~2^-14 relative
__device__ __forceinline__ void split_trunc(float v, short& hi, short& lo) {
  unsigned u = __float_as_uint(v);
  float hf = __uint_as_float(u & 0xffff0000u);
  hi = (short)(u >> 16);
  float r = v - hf;
  lo = (short)(__float_as_uint(r) >> 16);
}

// Packed B-fragment layout (validated round 3): short8 index (kb*4+tile)*64+lane,
// lane = kgrp*16 + n15 holds way tile*16+n15, k = kb*32 + kgrp*8 + j.

__global__ __launch_bounds__(512) void fused_kernel(
    const float* __restrict__ x, unsigned short* __restrict__ phi,
    unsigned short* __restrict__ plo, float* __restrict__ pnorm,
    unsigned* __restrict__ ctr, float* __restrict__ out) {
  __shared__ float Sp[8][16][68];   // per-wave partial tiles (padded)
  __shared__ float So[16][68];      // reduced logits

  const int tid  = threadIdx.x;
  const int wv   = tid >> 6;        // 0..7: K-slice owner in gemm phase
  const int lane = tid & 63;
  const int lrow = lane & 15;
  const int kgrp = lane >> 4;
  const int qb   = blockIdx.x * QT;

  // ---- issue A-loads early (16 query rows, f32): latency hides under proto ----
  const int qrow = (qb >> 6) * ROWS_PER_WAY + N_SUP + (qb & 63) + lrow;
  const float* arow = x + (size_t)qrow * DIM + kgrp * 8;
  f32x4 a0[4], a1[4];
  #pragma unroll
  for (int s = 0; s < 4; ++s) {
    const int kb = wv * 4 + s;
    a0[s] = *(const f32x4*)(arow + kb * 32);
    a1[s] = *(const f32x4*)(arow + kb * 32 + 4);
  }

  // ---- proto phase: block handles quarter (blk&3) of way (blk>>2) ----
  {
    const int way = blockIdx.x >> 2;
    const int col = (blockIdx.x & 3) * 64 + (tid >> 3);  // f32x4 column 0..255
    const int sub = tid & 7;                             // support pair owner
    const float4* x4 = (const float4*)x;
    const int pb = way * ROWS_PER_WAY * (DIM / 4);
    float4 s0 = x4[pb + (sub * 2) * (DIM / 4) + col];
    float4 s1 = x4[pb + (sub * 2 + 1) * (DIM / 4) + col];
    float ax = s0.x + s1.x, ay = s0.y + s1.y;
    float az = s0.z + s1.z, aw = s0.w + s1.w;
    #pragma unroll
    for (int off = 4; off; off >>= 1) {
      ax += __shfl_down(ax, off); ay += __shfl_down(ay, off);
      az += __shfl_down(az, off); aw += __shfl_down(aw, off);
    }
    float pq = 0.f;
    if (sub == 0) {
      const float inv = 1.0f / 16.0f;
      ax *= inv; ay *= inv; az *= inv; aw *= inv;
      float vals[4] = {ax, ay, az, aw};
      short hh[4], ll[4];
      #pragma unroll
      for (int j = 0; j < 4; ++j) split_trunc(vals[j], hh[j], ll[j]);
      const int kb2 = col >> 3, kg2 = (col >> 1) & 3, j0 = (col & 1) * 4;
      const int tile = way >> 4;
      const int ln = kg2 * 16 + (way & 15);
      const int uidx = ((kb2 * 4 + tile) * 64 + ln) * 8 + j0;
      *(ushort4*)(phi + uidx) = make_ushort4((unsigned short)hh[0], (unsigned short)hh[1],
                                             (unsigned short)hh[2], (unsigned short)hh[3]);
      *(ushort4*)(plo + uidx) = make_ushort4((unsigned short)ll[0], (unsigned short)ll[1],
                                             (unsigned short)ll[2], (unsigned short)ll[3]);
      pq = ax * ax + ay * ay + az * az + aw * aw;
    }
    pq += __shfl_down(pq, 32);
    pq += __shfl_down(pq, 16);
    pq += __shfl_down(pq, 8);
    if (lane == 0) atomicAdd(&pnorm[way], pq);
  }

  // ---- convert A to bf16 hi/lo while proto stores drain ----
  short8 ah[4], al[4];
  #pragma unroll
  for (int s = 0; s < 4; ++s)
    #pragma unroll
    for (int j = 0; j < 4; ++j) {
      short h, l;
      split_trunc(a0[s][j], h, l); ah[s][j] = h; al[s][j] = l;
      split_trunc(a1[s][j], h, l); ah[s][4 + j] = h; al[s][4 + j] = l;
    }

  // ---- device-wide flag sync: release our proto data, acquire everyone's ----
  __threadfence();           // writeback dirty L2 (agent release)
  __syncthreads();           // all block stores drained (vmcnt 0 at barrier)
  if (tid == 0) {
    __hip_atomic_fetch_add(ctr, 1u, __ATOMIC_RELEASE, __HIP_MEMORY_SCOPE_AGENT);
    while (__hip_atomic_load(ctr, __ATOMIC_ACQUIRE, __HIP_MEMORY_SCOPE_AGENT) < NBLK)
      __builtin_amdgcn_s_sleep(2);
    // acquire invalidated L1/L2: cross-XCD (and cross-replay) phi/plo now fresh
  }
  __syncthreads();

  // ---- gemm: S = 2*q.p - ||p||^2 via split-bf16 MFMA ----
  f32x4 acc[4];
  #pragma unroll
  for (int t = 0; t < 4; ++t) acc[t] = (f32x4){0.f, 0.f, 0.f, 0.f};
  const short8* bhp = (const short8*)phi + lane;
  const short8* blp = (const short8*)plo + lane;
  #pragma unroll
  for (int s = 0; s < 4; ++s) {
    const int kb = wv * 4 + s;
    #pragma unroll
    for (int t = 0; t < 4; ++t) {
      short8 bhv = bhp[(kb * 4 + t) * 64];
      short8 blv = blp[(kb * 4 + t) * 64];
      acc[t] = __builtin_amdgcn_mfma_f32_16x16x32_bf16(ah[s], bhv, acc[t], 0, 0, 0);
      acc[t] = __builtin_amdgcn_mfma_f32_16x16x32_bf16(ah[s], blv, acc[t], 0, 0, 0);
      acc[t] = __builtin_amdgcn_mfma_f32_16x16x32_bf16(al[s], bhv, acc[t], 0, 0, 0);
    }
  }

  // per-wave partials: C/D layout col(way)=lane&15, row(q)=kgrp*4+r
  #pragma unroll
  for (int t = 0; t < 4; ++t)
    #pragma unroll
    for (int r = 0; r < 4; ++r)
      Sp[wv][kgrp * 4 + r][t * 16 + lrow] = acc[t][r];
  __syncthreads();

  // reduce 8 K-slices, apply 2*dot - pnorm
  for (int i = tid; i < QT * N_WAY; i += 512) {
    int q = i >> 6, w = i & 63;
    float s = 0.f;
    #pragma unroll
    for (int v = 0; v < 8; ++v) s += Sp[v][q][w];
    So[q][w] = 2.f * s - pnorm[w];
  }
  __syncthreads();

  // fused log-softmax + argmax: wave 0, 64 lanes = 16 q x 4 way-quarters
  if (tid < 64) {
    const int q = lane & 15;
    const int wq = lane >> 4;
    const int label = qb >> 6;
    float m = -INFINITY; int arg = 0;
    #pragma unroll
    for (int i = 0; i < 16; ++i) {
      int w = wq * 16 + i;
      float v = So[q][w];
      if (v > m) { m = v; arg = w; }
    }
    #pragma unroll
    for (int off = 16; off < 64; off <<= 1) {
      float om = __shfl_xor(m, off);
      int oa = __shfl_xor(arg, off);
      if (om > m || (om == m && oa < arg)) { m = om; arg = oa; }
    }
    float sum = 0.f;
    #pragma unroll
    for (int i = 0; i < 16; ++i) sum += expf(So[q][wq * 16 + i] - m);
    sum += __shfl_xor(sum, 16);
    sum += __shfl_xor(sum, 32);

    float lossq = 0.f, corr = 0.f;
    if (lane < 16) {
      lossq = m + logf(sum) - So[q][label];
      corr = (arg == label) ? 1.f : 0.f;
    }
    #pragma unroll
    for (int off = 8; off > 0; off >>= 1) {
      lossq += __shfl_down(lossq, off);
      corr  += __shfl_down(corr, off);
    }
    if (lane == 0) {
      atomicAdd(&out[0], lossq * (1.0f / (float)N_QUERIES));
      atomicAdd(&out[1], corr * (100.0f / (float)N_QUERIES));
    }
  }
}

extern "C" void kernel_launch(void* const* d_in, const int* in_sizes, int n_in,
                              void* d_out, int out_size, void* d_ws, size_t ws_size,
                              hipStream_t stream) {
  (void)in_sizes; (void)n_in; (void)out_size; (void)ws_size;
  const float* x = (const float*)d_in[0];
  float* out = (float*)d_out;

  unsigned short* phi = (unsigned short*)d_ws;        // 64*1024 u16 packed
  unsigned short* plo = phi + N_WAY * DIM;            // 64*1024 u16 packed
  float* pnorm = (float*)(plo + N_WAY * DIM);         // 64 f32
  unsigned* ctr = (unsigned*)(pnorm + N_WAY);         // 1 u32

  // zero the accumulator/flag region and the output (graph-capturable)
  hipMemsetAsync(pnorm, 0, N_WAY * sizeof(float) + sizeof(unsigned), stream);
  hipMemsetAsync(out, 0, 2 * sizeof(float), stream);

  hipLaunchKernelGGL(fused_kernel, dim3(NBLK), dim3(512), 0, stream,
                     x, phi, plo, pnorm, ctr, out);
}

// Round 5
// 18.881 us; speedup vs baseline: 4.7819x; 4.7819x over previous
//
#include <hip/hip_runtime.h>
#include <math.h>

#define N_WAY 64
#define N_SUP 16
#define DIM   1024
#define N_QUERIES 4096
#define ROWS_PER_WAY 80
#define QT 16
#define GEMM_BLOCKS 256   // N_QUERIES / QT

typedef __attribute__((ext_vector_type(8))) short short8;
typedef __attribute__((ext_vector_type(4))) float f32x4;

// Truncation split: v ~= hi + lo (both bf16), error ~2^-14 relative
__device__ __forceinline__ void split_trunc(float v, short& hi, short& lo) {
  unsigned u = __float_as_uint(v);
  float hf = __uint_as_float(u & 0xffff0000u);
  hi = (short)(u >> 16);
  float r = v - hf;
  lo = (short)(__float_as_uint(r) >> 16);
}

// Packed B-fragment layout (validated round 3): short8 index (kb*4+tile)*64+lane,
// lane = kgrp*16 + n15 holds way tile*16+n15, k = kb*32 + kgrp*8 + j.

// ---------------------------------------------------------------------------
// Kernel A: prototypes. grid = 256 (4 blocks per way, 64 f32x4-cols each),
// block = 256 (4 waves; wave sg sums support rows 4sg..4sg+3). No atomics:
// per-(way,quarter) pnorm partials via plain stores, summed in gemm.
// ---------------------------------------------------------------------------
__global__ __launch_bounds__(256) void proto_kernel(
    const float* __restrict__ x, unsigned short* __restrict__ phi,
    unsigned short* __restrict__ plo, float* __restrict__ pnorm4) {
  const int way = blockIdx.x >> 2;
  const int cg  = blockIdx.x & 3;       // column quarter
  const int t   = threadIdx.x;
  const int lc  = t & 63;               // local f32x4 col
  const int sg  = t >> 6;               // support group (4 rows)
  const float4* x4 = (const float4*)x;
  const int base = way * ROWS_PER_WAY * (DIM / 4);
  const int col = cg * 64 + lc;         // f32x4 col 0..255

  float4 a = make_float4(0.f, 0.f, 0.f, 0.f);
  #pragma unroll
  for (int r = 0; r < 4; ++r) {
    float4 v = x4[base + (sg * 4 + r) * (DIM / 4) + col];
    a.x += v.x; a.y += v.y; a.z += v.z; a.w += v.w;
  }
  __shared__ float4 pars[4][64];
  pars[sg][lc] = a;
  __syncthreads();

  if (t < 64) {
    float4 a0 = pars[0][t], a1 = pars[1][t], a2 = pars[2][t], a3 = pars[3][t];
    const float inv = 1.0f / 16.0f;
    float vals[4] = {(a0.x + a1.x + a2.x + a3.x) * inv,
                     (a0.y + a1.y + a2.y + a3.y) * inv,
                     (a0.z + a1.z + a2.z + a3.z) * inv,
                     (a0.w + a1.w + a2.w + a3.w) * inv};
    short hh[4], ll[4];
    #pragma unroll
    for (int j = 0; j < 4; ++j) split_trunc(vals[j], hh[j], ll[j]);

    const int c   = cg * 64 + t;        // f32x4 col 0..255
    const int kb2 = c >> 3, kg2 = (c >> 1) & 3, j0 = (c & 1) * 4;
    const int tile = way >> 4;
    const int ln = kg2 * 16 + (way & 15);
    const int uidx = ((kb2 * 4 + tile) * 64 + ln) * 8 + j0;
    *(ushort4*)(phi + uidx) = make_ushort4((unsigned short)hh[0], (unsigned short)hh[1],
                                           (unsigned short)hh[2], (unsigned short)hh[3]);
    *(ushort4*)(plo + uidx) = make_ushort4((unsigned short)ll[0], (unsigned short)ll[1],
                                           (unsigned short)ll[2], (unsigned short)ll[3]);

    float pq = vals[0] * vals[0] + vals[1] * vals[1] +
               vals[2] * vals[2] + vals[3] * vals[3];
    #pragma unroll
    for (int off = 32; off > 0; off >>= 1) pq += __shfl_down(pq, off);
    if (t == 0) pnorm4[way * 4 + cg] = pq;   // plain store, no atomic
  }
}

// ---------------------------------------------------------------------------
// Kernel B: split-bf16 MFMA gemm + fused per-tile softmax. NO atomics, NO
// fences: each block writes (loss_sum, correct_count) to part[blk] via plain
// stores. grid = 256, block = 512 (wave wv owns K-range [wv*128, +128)).
// ---------------------------------------------------------------------------
__global__ __launch_bounds__(512, 1) void gemm_kernel(
    const float* __restrict__ x, const unsigned short* __restrict__ phi,
    const unsigned short* __restrict__ plo, const float* __restrict__ pnorm4,
    float* __restrict__ part) {
  __shared__ float Sp[8][16][68];   // per-wave partial tiles (padded)
  __shared__ float So[16][68];      // reduced logits
  __shared__ float pnL[64];

  const int tid  = threadIdx.x;
  const int wv   = tid >> 6;
  const int lane = tid & 63;
  const int lrow = lane & 15;
  const int kgrp = lane >> 4;
  const int qb   = blockIdx.x * QT;

  // ---- A: load all 8 f32x4 (this wave's K-slice of 16 query rows) ----
  const int qrow = (qb >> 6) * ROWS_PER_WAY + N_SUP + (qb & 63) + lrow;
  const float* arow = x + (size_t)qrow * DIM + kgrp * 8;
  f32x4 a0[4], a1[4];
  #pragma unroll
  for (int s = 0; s < 4; ++s) {
    const int kb = wv * 4 + s;
    a0[s] = *(const f32x4*)(arow + kb * 32);
    a1[s] = *(const f32x4*)(arow + kb * 32 + 4);
  }
  short8 ah[4], al[4];
  #pragma unroll
  for (int s = 0; s < 4; ++s)
    #pragma unroll
    for (int j = 0; j < 4; ++j) {
      short h, l;
      split_trunc(a0[s][j], h, l); ah[s][j] = h; al[s][j] = l;
      split_trunc(a1[s][j], h, l); ah[s][4 + j] = h; al[s][4 + j] = l;
    }

  // ---- gemm: batch 8 B-loads per K-step, then 12 MFMAs ----
  f32x4 acc[4];
  #pragma unroll
  for (int t = 0; t < 4; ++t) acc[t] = (f32x4){0.f, 0.f, 0.f, 0.f};
  const short8* bhp = (const short8*)phi + lane;
  const short8* blp = (const short8*)plo + lane;
  #pragma unroll
  for (int s = 0; s < 4; ++s) {
    const int kb = wv * 4 + s;
    short8 bhv[4], blv[4];
    #pragma unroll
    for (int t = 0; t < 4; ++t) {
      bhv[t] = bhp[(kb * 4 + t) * 64];
      blv[t] = blp[(kb * 4 + t) * 64];
    }
    #pragma unroll
    for (int t = 0; t < 4; ++t) {
      acc[t] = __builtin_amdgcn_mfma_f32_16x16x32_bf16(ah[s], bhv[t], acc[t], 0, 0, 0);
      acc[t] = __builtin_amdgcn_mfma_f32_16x16x32_bf16(ah[s], blv[t], acc[t], 0, 0, 0);
      acc[t] = __builtin_amdgcn_mfma_f32_16x16x32_bf16(al[s], bhv[t], acc[t], 0, 0, 0);
    }
  }

  // per-wave partials: C/D layout col(way)=lane&15, row(q)=kgrp*4+r (validated)
  #pragma unroll
  for (int t = 0; t < 4; ++t)
    #pragma unroll
    for (int r = 0; r < 4; ++r)
      Sp[wv][kgrp * 4 + r][t * 16 + lrow] = acc[t][r];
  if (tid < 64)
    pnL[tid] = pnorm4[4 * tid] + pnorm4[4 * tid + 1] +
               pnorm4[4 * tid + 2] + pnorm4[4 * tid + 3];
  __syncthreads();

  // reduce 8 K-slices, apply 2*dot - pnorm
  for (int i = tid; i < QT * N_WAY; i += 512) {
    int q = i >> 6, w = i & 63;
    float s = 0.f;
    #pragma unroll
    for (int v = 0; v < 8; ++v) s += Sp[v][q][w];
    So[q][w] = 2.f * s - pnL[w];
  }
  __syncthreads();

  // fused log-softmax + argmax: wave 0, 64 lanes = 16 q x 4 way-quarters
  if (tid < 64) {
    const int q = lane & 15;
    const int wq = lane >> 4;
    const int label = qb >> 6;
    float m = -INFINITY; int arg = 0;
    #pragma unroll
    for (int i = 0; i < 16; ++i) {
      int w = wq * 16 + i;
      float v = So[q][w];
      if (v > m) { m = v; arg = w; }
    }
    #pragma unroll
    for (int off = 16; off < 64; off <<= 1) {
      float om = __shfl_xor(m, off);
      int oa = __shfl_xor(arg, off);
      if (om > m || (om == m && oa < arg)) { m = om; arg = oa; }
    }
    float sum = 0.f;
    #pragma unroll
    for (int i = 0; i < 16; ++i) sum += expf(So[q][wq * 16 + i] - m);
    sum += __shfl_xor(sum, 16);
    sum += __shfl_xor(sum, 32);

    float lossq = 0.f, corr = 0.f;
    if (lane < 16) {
      lossq = m + logf(sum) - So[q][label];
      corr = (arg == label) ? 1.f : 0.f;
    }
    #pragma unroll
    for (int off = 8; off > 0; off >>= 1) {
      lossq += __shfl_down(lossq, off);
      corr  += __shfl_down(corr, off);
    }
    if (lane == 0) {   // plain stores — no atomics, no fence
      part[2 * blockIdx.x]     = lossq;
      part[2 * blockIdx.x + 1] = corr;
    }
  }
}

// ---------------------------------------------------------------------------
// Kernel C: reduce 256 partials -> out. 1 block x 256 threads.
// ---------------------------------------------------------------------------
__global__ __launch_bounds__(256) void finalize_kernel(
    const float* __restrict__ part, float* __restrict__ out) {
  const int t = threadIdx.x;
  float l = part[2 * t], c = part[2 * t + 1];
  #pragma unroll
  for (int off = 32; off > 0; off >>= 1) {
    l += __shfl_down(l, off);
    c += __shfl_down(c, off);
  }
  __shared__ float rl[4], rc[4];
  if ((t & 63) == 0) { rl[t >> 6] = l; rc[t >> 6] = c; }
  __syncthreads();
  if (t == 0) {
    out[0] = (rl[0] + rl[1] + rl[2] + rl[3]) * (1.0f / (float)N_QUERIES);
    out[1] = (rc[0] + rc[1] + rc[2] + rc[3]) * (100.0f / (float)N_QUERIES);
  }
}

extern "C" void kernel_launch(void* const* d_in, const int* in_sizes, int n_in,
                              void* d_out, int out_size, void* d_ws, size_t ws_size,
                              hipStream_t stream) {
  (void)in_sizes; (void)n_in; (void)out_size; (void)ws_size;
  const float* x = (const float*)d_in[0];
  float* out = (float*)d_out;

  unsigned short* phi = (unsigned short*)d_ws;        // 64*1024 u16 packed
  unsigned short* plo = phi + N_WAY * DIM;            // 64*1024 u16 packed
  float* pnorm4 = (float*)(plo + N_WAY * DIM);        // 256 f32
  float* part   = pnorm4 + 256;                       // 512 f32

  hipLaunchKernelGGL(proto_kernel, dim3(256), dim3(256), 0, stream,
                     x, phi, plo, pnorm4);
  hipLaunchKernelGGL(gemm_kernel, dim3(GEMM_BLOCKS), dim3(512), 0, stream,
                     x, phi, plo, pnorm4, part);
  hipLaunchKernelGGL(finalize_kernel, dim3(1), dim3(256), 0, stream,
                     part, out);
}

// Round 6
// 16.953 us; speedup vs baseline: 5.3256x; 1.1137x over previous
//
#include <hip/hip_runtime.h>
#include <math.h>

#define N_WAY 64
#define N_SUP 16
#define DIM   1024
#define N_QUERIES 4096
#define ROWS_PER_WAY 80
#define QT 16
#define GEMM_BLOCKS 256   // N_QUERIES / QT

typedef __attribute__((ext_vector_type(8))) short short8;
typedef __attribute__((ext_vector_type(4))) float f32x4;

// bf16 round-to-nearest-even
__device__ __forceinline__ unsigned short bf16_rne(float f) {
  unsigned u = __float_as_uint(f);
  return (unsigned short)((u + 0x7fffu + ((u >> 16) & 1u)) >> 16);
}

// Packed B-fragment layout (validated round 3): short8 index (kb*4+tile)*64+lane,
// lane = kgrp*16 + n15 holds way tile*16+n15, k = kb*32 + kgrp*8 + j.

// ---------------------------------------------------------------------------
// Kernel A: prototypes -> packed bf16 fragments + per-quarter pnorm partials.
// grid = 256 (4 blocks per way), block = 256. No atomics.
// ---------------------------------------------------------------------------
__global__ __launch_bounds__(256) void proto_kernel(
    const float* __restrict__ x, unsigned short* __restrict__ phi,
    float* __restrict__ pnorm4) {
  const int way = blockIdx.x >> 2;
  const int cg  = blockIdx.x & 3;       // column quarter
  const int t   = threadIdx.x;
  const int lc  = t & 63;               // local f32x4 col
  const int sg  = t >> 6;               // support group (4 rows)
  const float4* x4 = (const float4*)x;
  const int base = way * ROWS_PER_WAY * (DIM / 4);
  const int col = cg * 64 + lc;         // f32x4 col 0..255

  float4 a = make_float4(0.f, 0.f, 0.f, 0.f);
  #pragma unroll
  for (int r = 0; r < 4; ++r) {
    float4 v = x4[base + (sg * 4 + r) * (DIM / 4) + col];
    a.x += v.x; a.y += v.y; a.z += v.z; a.w += v.w;
  }
  __shared__ float4 pars[4][64];
  pars[sg][lc] = a;
  __syncthreads();

  if (t < 64) {
    float4 a0 = pars[0][t], a1 = pars[1][t], a2 = pars[2][t], a3 = pars[3][t];
    const float inv = 1.0f / 16.0f;
    float vals[4] = {(a0.x + a1.x + a2.x + a3.x) * inv,
                     (a0.y + a1.y + a2.y + a3.y) * inv,
                     (a0.z + a1.z + a2.z + a3.z) * inv,
                     (a0.w + a1.w + a2.w + a3.w) * inv};
    const int c   = cg * 64 + t;        // f32x4 col 0..255
    const int kb2 = c >> 3, kg2 = (c >> 1) & 3, j0 = (c & 1) * 4;
    const int tile = way >> 4;
    const int ln = kg2 * 16 + (way & 15);
    const int uidx = ((kb2 * 4 + tile) * 64 + ln) * 8 + j0;
    *(ushort4*)(phi + uidx) = make_ushort4(bf16_rne(vals[0]), bf16_rne(vals[1]),
                                           bf16_rne(vals[2]), bf16_rne(vals[3]));

    float pq = vals[0] * vals[0] + vals[1] * vals[1] +
               vals[2] * vals[2] + vals[3] * vals[3];
    #pragma unroll
    for (int off = 32; off > 0; off >>= 1) pq += __shfl_down(pq, off);
    if (t == 0) pnorm4[way * 4 + cg] = pq;   // plain store, no atomic
  }
}

// ---------------------------------------------------------------------------
// Kernel B: bf16 MFMA gemm + fused per-tile softmax. Plain stores of per-block
// (loss, correct) partials. grid = 256, block = 512; wave wv owns K-slice
// [wv*128, wv*128+128). 16 MFMAs / 16 B-loads per wave.
// ---------------------------------------------------------------------------
__global__ __launch_bounds__(512) void gemm_kernel(
    const float* __restrict__ x, const unsigned short* __restrict__ phi,
    const float* __restrict__ pnorm4, float* __restrict__ part) {
  __shared__ float Sp[8][16][68];   // per-wave partial tiles (padded)
  __shared__ float So[16][68];      // reduced logits
  __shared__ float pnL[64];

  const int tid  = threadIdx.x;
  const int wv   = tid >> 6;
  const int lane = tid & 63;
  const int lrow = lane & 15;
  const int kgrp = lane >> 4;
  const int qb   = blockIdx.x * QT;

  // ---- issue all B loads first (16 x 1KB coalesced), then A loads ----
  const short8* bhp = (const short8*)phi + lane;
  short8 bhv[4][4];
  #pragma unroll
  for (int s = 0; s < 4; ++s)
    #pragma unroll
    for (int t = 0; t < 4; ++t)
      bhv[s][t] = bhp[((wv * 4 + s) * 4 + t) * 64];

  const int qrow = (qb >> 6) * ROWS_PER_WAY + N_SUP + (qb & 63) + lrow;
  const float* arow = x + (size_t)qrow * DIM + kgrp * 8;
  f32x4 a0[4], a1[4];
  #pragma unroll
  for (int s = 0; s < 4; ++s) {
    a0[s] = *(const f32x4*)(arow + (wv * 4 + s) * 32);
    a1[s] = *(const f32x4*)(arow + (wv * 4 + s) * 32 + 4);
  }
  if (tid < 64)
    pnL[tid] = pnorm4[4 * tid] + pnorm4[4 * tid + 1] +
               pnorm4[4 * tid + 2] + pnorm4[4 * tid + 3];

  // ---- convert A to bf16 (RNE) ----
  short8 ah[4];
  #pragma unroll
  for (int s = 0; s < 4; ++s)
    #pragma unroll
    for (int j = 0; j < 4; ++j) {
      ah[s][j]     = (short)bf16_rne(a0[s][j]);
      ah[s][4 + j] = (short)bf16_rne(a1[s][j]);
    }

  // ---- 16 MFMAs ----
  f32x4 acc[4];
  #pragma unroll
  for (int t = 0; t < 4; ++t) acc[t] = (f32x4){0.f, 0.f, 0.f, 0.f};
  #pragma unroll
  for (int s = 0; s < 4; ++s)
    #pragma unroll
    for (int t = 0; t < 4; ++t)
      acc[t] = __builtin_amdgcn_mfma_f32_16x16x32_bf16(ah[s], bhv[s][t], acc[t], 0, 0, 0);

  // per-wave partials: C/D layout col(way)=lane&15, row(q)=kgrp*4+r (validated)
  #pragma unroll
  for (int t = 0; t < 4; ++t)
    #pragma unroll
    for (int r = 0; r < 4; ++r)
      Sp[wv][kgrp * 4 + r][t * 16 + lrow] = acc[t][r];
  __syncthreads();

  // reduce 8 K-slices, apply 2*dot - pnorm
  for (int i = tid; i < QT * N_WAY; i += 512) {
    int q = i >> 6, w = i & 63;
    float s = 0.f;
    #pragma unroll
    for (int v = 0; v < 8; ++v) s += Sp[v][q][w];
    So[q][w] = 2.f * s - pnL[w];
  }
  __syncthreads();

  // fused log-softmax + argmax: wave 0, 64 lanes = 16 q x 4 way-quarters
  if (tid < 64) {
    const int q = lane & 15;
    const int wq = lane >> 4;
    const int label = qb >> 6;
    float m = -INFINITY; int arg = 0;
    #pragma unroll
    for (int i = 0; i < 16; ++i) {
      int w = wq * 16 + i;
      float v = So[q][w];
      if (v > m) { m = v; arg = w; }
    }
    #pragma unroll
    for (int off = 16; off < 64; off <<= 1) {
      float om = __shfl_xor(m, off);
      int oa = __shfl_xor(arg, off);
      if (om > m || (om == m && oa < arg)) { m = om; arg = oa; }
    }
    float sum = 0.f;
    #pragma unroll
    for (int i = 0; i < 16; ++i) sum += expf(So[q][wq * 16 + i] - m);
    sum += __shfl_xor(sum, 16);
    sum += __shfl_xor(sum, 32);

    float lossq = 0.f, corr = 0.f;
    if (lane < 16) {
      lossq = m + logf(sum) - So[q][label];
      corr = (arg == label) ? 1.f : 0.f;
    }
    #pragma unroll
    for (int off = 8; off > 0; off >>= 1) {
      lossq += __shfl_down(lossq, off);
      corr  += __shfl_down(corr, off);
    }
    if (lane == 0) {   // plain stores — no atomics, no fence
      part[2 * blockIdx.x]     = lossq;
      part[2 * blockIdx.x + 1] = corr;
    }
  }
}

// ---------------------------------------------------------------------------
// Kernel C: reduce 256 partial pairs -> out. 1 wave.
// part as float4: {loss(2i), corr(2i), loss(2i+1), corr(2i+1)}
// ---------------------------------------------------------------------------
__global__ __launch_bounds__(64) void finalize_kernel(
    const float* __restrict__ part, float* __restrict__ out) {
  const int t = threadIdx.x;
  const float4* p4 = (const float4*)part;
  float4 v0 = p4[t], v1 = p4[64 + t];
  float l = v0.x + v0.z + v1.x + v1.z;
  float c = v0.y + v0.w + v1.y + v1.w;
  #pragma unroll
  for (int off = 32; off > 0; off >>= 1) {
    l += __shfl_down(l, off);
    c += __shfl_down(c, off);
  }
  if (t == 0) {
    out[0] = l * (1.0f / (float)N_QUERIES);
    out[1] = c * (100.0f / (float)N_QUERIES);
  }
}

extern "C" void kernel_launch(void* const* d_in, const int* in_sizes, int n_in,
                              void* d_out, int out_size, void* d_ws, size_t ws_size,
                              hipStream_t stream) {
  (void)in_sizes; (void)n_in; (void)out_size; (void)ws_size;
  const float* x = (const float*)d_in[0];
  float* out = (float*)d_out;

  unsigned short* phi = (unsigned short*)d_ws;        // 64*1024 u16 packed
  float* pnorm4 = (float*)(phi + N_WAY * DIM);        // 256 f32
  float* part   = pnorm4 + 256;                       // 512 f32

  hipLaunchKernelGGL(proto_kernel, dim3(256), dim3(256), 0, stream,
                     x, phi, pnorm4);
  hipLaunchKernelGGL(gemm_kernel, dim3(GEMM_BLOCKS), dim3(512), 0, stream,
                     x, phi, pnorm4, part);
  hipLaunchKernelGGL(finalize_kernel, dim3(1), dim3(64), 0, stream,
                     part, out);
}